// Round 8
// baseline (306.168 us; speedup 1.0000x reference)
//
#include <hip/hip_runtime.h>
#include <math.h>

typedef short  short8  __attribute__((ext_vector_type(8)));
typedef short  short4v __attribute__((ext_vector_type(4)));
typedef float  f32x4   __attribute__((ext_vector_type(4)));

#define BATCH 32768
#define DIN   256
#define DOUT  512
#define BM    128
#define BN    64

// ws layout (bytes)
#define WS_FLAGS 0
#define WS_WD2   4096
#define WS_WR2   (4096 + 262144)
#define WS_X2    (266240 + 524288)

// round-to-nearest-even fp32 -> bf16 bits
__device__ __forceinline__ short f2bf(float v) {
    unsigned u = __float_as_uint(v);
    u += 0x7fffu + ((u >> 16) & 1u);
    return (short)(u >> 16);
}

// ---------------------------------------------------------------------------
// Fused pre-pass (one launch, 2048 blocks x 256):
//   A) SPK flag scan (64 MB) -> atomicOr into flags[bm]
//   B) X fp32 -> bf16 (33.5 MB rd, 16.7 MB wr)
//   C) Wd+Wr fp32 -> bf16 (4.5 MB)
// ---------------------------------------------------------------------------
__global__ __launch_bounds__(256) void prepass_kernel(
    const float* __restrict__ SPK, const float* __restrict__ X,
    const float* __restrict__ Wd,  const float* __restrict__ Wr,
    int* __restrict__ flags, short* __restrict__ X2,
    short* __restrict__ Wd2, short* __restrict__ Wr2)
{
    const int b   = blockIdx.x;      // 0..2047
    const int tid = threadIdx.x;

    // A) flag scan: block b covers float4 [b*2048, b*2048+2048) = 16 SPK rows
    {
        unsigned bits = 0;
        const f32x4* p = (const f32x4*)SPK + (size_t)b * 2048;
#pragma unroll
        for (int j = 0; j < 8; j++) {
            f32x4 v = p[tid + j * 256];
            bits |= __float_as_uint(v[0]) | __float_as_uint(v[1])
                  | __float_as_uint(v[2]) | __float_as_uint(v[3]);
        }
        if (__any(bits != 0) && (tid & 63) == 0)
            atomicOr(&flags[b >> 3], 1);
    }

    // B) X convert: block b covers float4 [b*1024, b*1024+1024)
    {
        const f32x4* src = (const f32x4*)X + (size_t)b * 1024;
        short4v*     dst = (short4v*)X2   + (size_t)b * 1024;
#pragma unroll
        for (int j = 0; j < 4; j++) {
            f32x4 v = src[tid + j * 256];
            dst[tid + j * 256] = (short4v){f2bf(v[0]), f2bf(v[1]),
                                           f2bf(v[2]), f2bf(v[3])};
        }
    }

    // C) weights: 32768 f4 (Wd) + 65536 f4 (Wr), first 98304 threads
    {
        int idx = b * 256 + tid;
        if (idx < 32768) {
            f32x4 v = ((const f32x4*)Wd)[idx];
            ((short4v*)Wd2)[idx] = (short4v){f2bf(v[0]), f2bf(v[1]),
                                             f2bf(v[2]), f2bf(v[3])};
        } else if (idx < 98304) {
            int k = idx - 32768;
            f32x4 v = ((const f32x4*)Wr)[k];
            ((short4v*)Wr2)[k] = (short4v){f2bf(v[0]), f2bf(v[1]),
                                           f2bf(v[2]), f2bf(v[3])};
        }
    }
}

// ---------------------------------------------------------------------------
// Main kernel. Block = 128(m) x 64(n), 4 waves as 2x2 of 64x32 wave tiles.
// XCD swizzle: the 8 bn-blocks sharing an X2 m-slice are consecutive
// dispatches on one XCD -> X2 re-reads are L2-local (r7: FETCH 98->42 MB).
//
// r7 diagnosis: VGPR=76 starved the allocator; a0/a1/b0/b1 were aliased to
// the same physical regs -> each wave held ~1 outstanding load (measured
// 8.9 GB/s/CU = 8 waves x 1KB/900ns exactly). r8: launch_bounds(256,2)
// raises the reg cap to ~256 (occupancy unchanged at 8 waves/CU), and the
// epilogue MEM prefetch moves to AFTER the K-loop so it neither holds 32
// regs across the loop nor blocks the vmcnt FIFO ahead of the first MFMA.
// ---------------------------------------------------------------------------
__global__ __launch_bounds__(256, 2) void spike_rnn_lif_kernel(
    const short* __restrict__ X2,   // bf16 [B, 256]
    const float* __restrict__ MEM,  // [B, 512]
    const float* __restrict__ SPK,  // [B, 512]
    const short* __restrict__ Wd2,  // bf16 [512, 256]
    const float* __restrict__ bd,   // [512]
    const short* __restrict__ Wr2,  // bf16 [512, 512]
    const float* __restrict__ br,   // [512]
    const float* __restrict__ tau,  // [512]
    const int*   __restrict__ flags,// [256]
    float* __restrict__ out)        // [2, B, 512]
{
    __shared__ float sT[64 * 68];   // 17.4 KB transpose buffer

    const int tid  = threadIdx.x;
    const int lane = tid & 63;
    const int w    = tid >> 6;
    const int wm   = w & 1;
    const int wn   = w >> 1;

    // XCD swizzle decode (bijective): L = ((bm/8)*8 + bn)*8 + bm%8
    const int L    = blockIdx.x;
    const int bm   = ((L >> 6) << 3) + (L & 7);
    const int bn   = (L >> 3) & 7;
    const int m0   = bm * BM;
    const int n0   = bn * BN;
    const int col  = lane & 15;
    const int quad = lane >> 4;

    const bool has_spk = (flags[bm] != 0);

    f32x4 acc[4][2];
#pragma unroll
    for (int i = 0; i < 4; i++)
#pragma unroll
        for (int j = 0; j < 2; j++)
            acc[i][j] = (f32x4){0.f, 0.f, 0.f, 0.f};

    // ---- Phase 1: dense GEMM, K=256, barrier-free, 2-deep reg pipeline ----
    {
        const short* Abase = X2  + (size_t)(m0 + wm * 64 + col) * DIN + quad * 8;
        const short* Bbase = Wd2 + (size_t)(n0 + wn * 32 + col) * DIN + quad * 8;

#define LOAD_AB(kk, aa, bb)                                                   \
        do {                                                                  \
            int k_ = (kk) * 32;                                               \
            _Pragma("unroll")                                                 \
            for (int t = 0; t < 4; t++)                                       \
                aa[t] = *(const short8*)(Abase + (size_t)t * 16 * DIN + k_);  \
            _Pragma("unroll")                                                 \
            for (int t = 0; t < 2; t++)                                       \
                bb[t] = *(const short8*)(Bbase + (size_t)t * 16 * DIN + k_);  \
        } while (0)

#define MFMA_AB(aa, bb)                                                       \
        do {                                                                  \
            _Pragma("unroll")                                                 \
            for (int i = 0; i < 4; i++)                                       \
                _Pragma("unroll")                                             \
                for (int j = 0; j < 2; j++)                                   \
                    acc[i][j] = __builtin_amdgcn_mfma_f32_16x16x32_bf16(      \
                        aa[i], bb[j], acc[i][j], 0, 0, 0);                    \
        } while (0)

        short8 a0[4], b0[2], a1[4], b1[2];
        LOAD_AB(0, a0, b0);
#pragma unroll
        for (int kp = 0; kp < 4; kp++) {
            LOAD_AB(2 * kp + 1, a1, b1);
            MFMA_AB(a0, b0);
            if (kp < 3) LOAD_AB(2 * kp + 2, a0, b0);
            MFMA_AB(a1, b1);
        }
#undef LOAD_AB
    }

    // ---- Phase 2: recurrent GEMM, K=512 — only when spikes exist ----
    if (has_spk) {
        const float* Abase = SPK + (size_t)(m0 + wm * 64 + col) * DOUT + quad * 8;
        const short* Bbase = Wr2 + (size_t)(n0 + wn * 32 + col) * DOUT + quad * 8;
#pragma unroll 4
        for (int ks = 0; ks < 16; ks++) {
            int k = ks * 32;
            short8 a[4], b[2];
#pragma unroll
            for (int t = 0; t < 4; t++) {
                const float* ap = Abase + (size_t)t * 16 * DOUT + k;
                f32x4 lo = *(const f32x4*)ap;
                f32x4 hi = *(const f32x4*)(ap + 4);
                a[t] = (short8){f2bf(lo[0]), f2bf(lo[1]), f2bf(lo[2]), f2bf(lo[3]),
                                f2bf(hi[0]), f2bf(hi[1]), f2bf(hi[2]), f2bf(hi[3])};
            }
#pragma unroll
            for (int t = 0; t < 2; t++)
                b[t] = *(const short8*)(Bbase + (size_t)t * 16 * DOUT + k);
            MFMA_AB(a, b);
        }
    }
#undef MFMA_AB

    // ---- Epilogue prefetch: all 8 MEM vectors in flight together ----
    const int c4   = tid & 15;
    const int ncol = n0 + c4 * 4;
    f32x4 mv0[4], mv1[4];
#pragma unroll
    for (int it = 0; it < 4; it++) {
        int r2 = (tid + it * 256) >> 4;
        mv0[it] = __builtin_nontemporal_load(
                      (const f32x4*)(MEM + (size_t)(m0 + r2) * DOUT + ncol));
        mv1[it] = __builtin_nontemporal_load(
                      (const f32x4*)(MEM + (size_t)(m0 + 64 + r2) * DOUT + ncol));
    }

    float al[4], oma[4], bs[4];
#pragma unroll
    for (int q = 0; q < 4; q++) {
        al[q]  = expf(-1.0f / tau[ncol + q]);
        oma[q] = 1.0f - al[q];
        bs[q]  = bd[ncol + q] + br[ncol + q];
    }

#pragma unroll
    for (int c = 0; c < 2; c++) {
        if (c) __syncthreads();
        if (wm == c) {
            // C/D layout (verified): col = lane&15, row = quad*4 + reg
#pragma unroll
            for (int j = 0; j < 2; j++)
#pragma unroll
                for (int i = 0; i < 4; i++)
#pragma unroll
                    for (int rr = 0; rr < 4; rr++)
                        sT[(i * 16 + quad * 4 + rr) * 68 + wn * 32 + j * 16 + col]
                            = acc[i][j][rr];
        }
        __syncthreads();
#pragma unroll
        for (int it = 0; it < 4; it++) {
            int p   = tid + it * 256;
            int r2  = p >> 4;
            int row = m0 + c * 64 + r2;
            f32x4 d  = *(const f32x4*)(sT + r2 * 68 + c4 * 4);
            f32x4 mv = c ? mv1[it] : mv0[it];
            f32x4 sv = has_spk ? *(const f32x4*)(SPK + (size_t)row * DOUT + ncol)
                               : (f32x4){0.f, 0.f, 0.f, 0.f};
            f32x4 mn, sp;
#pragma unroll
            for (int q = 0; q < 4; q++) {
                mn[q] = mv[q] * al[q] + oma[q] * (d[q] + bs[q]) - 0.5f * sv[q];
                sp[q] = (mn[q] - 0.5f > 0.0f) ? 1.0f : 0.0f;
            }
            __builtin_nontemporal_store(mn,
                (f32x4*)(out + (size_t)row * DOUT + ncol));
            __builtin_nontemporal_store(sp,
                (f32x4*)(out + (size_t)BATCH * DOUT + (size_t)row * DOUT + ncol));
        }
    }
}

extern "C" void kernel_launch(void* const* d_in, const int* in_sizes, int n_in,
                              void* d_out, int out_size, void* d_ws, size_t ws_size,
                              hipStream_t stream) {
    const float* X   = (const float*)d_in[0];
    const float* MEM = (const float*)d_in[1];
    const float* SPK = (const float*)d_in[2];
    const float* Wd  = (const float*)d_in[3];
    const float* bd  = (const float*)d_in[4];
    const float* Wr  = (const float*)d_in[5];
    const float* br  = (const float*)d_in[6];
    const float* tau = (const float*)d_in[7];

    char*  ws    = (char*)d_ws;
    int*   flags = (int*)  (ws + WS_FLAGS);
    short* Wd2   = (short*)(ws + WS_WD2);
    short* Wr2   = (short*)(ws + WS_WR2);
    short* X2    = (short*)(ws + WS_X2);

    hipMemsetAsync(flags, 0, 256 * sizeof(int), stream);   // graph-capture-safe
    prepass_kernel<<<2048, 256, 0, stream>>>(SPK, X, Wd, Wr, flags, X2, Wd2, Wr2);

    spike_rnn_lif_kernel<<<2048, 256, 0, stream>>>(X2, MEM, SPK, Wd2, bd, Wr2, br,
                                                   tau, flags, (float*)d_out);
}